// Round 4
// baseline (385.322 us; speedup 1.0000x reference)
//
#include <hip/hip_runtime.h>
#include <hip/hip_bf16.h>

#define Bv 2
#define Tv 2048
#define Cv 1024
#define Hv 16
#define HSv 64
#define HIDv 2730
#define HIDP 2816
#define Mv 4096

using bf16x8 = __attribute__((ext_vector_type(8))) __bf16;
using f32x4  = __attribute__((ext_vector_type(4))) float;

__device__ __forceinline__ void gload_lds16(const void* g, void* l) {
    auto gp = (const __attribute__((address_space(1))) unsigned int*)(unsigned long long)(uintptr_t)g;
    auto lp = (__attribute__((address_space(3))) unsigned int*)(unsigned int)(uintptr_t)l;
    __builtin_amdgcn_global_load_lds(gp, lp, 16, 0, 0);
}

// ---------------- fused weight cast ----------------
struct CastSeg { const float* s; __bf16* d; long nsrc; long ntot; int sc; int dc; };
struct CastArgs { CastSeg seg[7]; };

__global__ __launch_bounds__(256) void k_castall(CastArgs a) {
    long gid = (long)blockIdx.x * 256 + threadIdx.x;
    long gstr = (long)gridDim.x * 256;
#pragma unroll 1
    for (int g = 0; g < 7; ++g) {
        CastSeg sg = a.seg[g];
        if (sg.sc == 0) {
            long n4 = sg.ntot >> 2;
            for (long i = gid; i < n4; i += gstr) {
                long base = i * 4;
                float4 v = {0.f, 0.f, 0.f, 0.f};
                if (base < sg.nsrc) v = *(const float4*)(sg.s + base);
                __bf16 o[4] = {(__bf16)v.x, (__bf16)v.y, (__bf16)v.z, (__bf16)v.w};
                *(unsigned long long*)(sg.d + base) = *(unsigned long long*)o;
            }
        } else {
            for (long i = gid; i < sg.ntot; i += gstr) {
                int r = (int)(i / sg.dc), c = (int)(i % sg.dc);
                sg.d[i] = (c < sg.sc) ? (__bf16)sg.s[(long)r * sg.sc + c] : (__bf16)0.0f;
            }
        }
    }
}

// ---------------- rmsnorm ----------------
__global__ __launch_bounds__(256) void k_rmsnorm(const float* __restrict__ x,
                                                 const float* __restrict__ w,
                                                 float* __restrict__ yf,
                                                 __bf16* __restrict__ yh) {
    int row = blockIdx.x;
    const float4* xr = (const float4*)(x + (size_t)row * Cv);
    float4 a = xr[threadIdx.x];
    float ss = a.x * a.x + a.y * a.y + a.z * a.z + a.w * a.w;
#pragma unroll
    for (int m = 1; m < 64; m <<= 1) ss += __shfl_xor(ss, m);
    __shared__ float red[4];
    if ((threadIdx.x & 63) == 0) red[threadIdx.x >> 6] = ss;
    __syncthreads();
    float tot = red[0] + red[1] + red[2] + red[3];
    float sc = rsqrtf(tot * (1.0f / Cv) + 1e-6f);
    float4 wv = ((const float4*)w)[threadIdx.x];
    float4 o;
    o.x = a.x * sc * wv.x; o.y = a.y * sc * wv.y;
    o.z = a.z * sc * wv.z; o.w = a.w * sc * wv.w;
    ((float4*)(yf + (size_t)row * Cv))[threadIdx.x] = o;
    __bf16* yp = yh + (size_t)row * Cv + threadIdx.x * 4;
    yp[0] = (__bf16)o.x; yp[1] = (__bf16)o.y; yp[2] = (__bf16)o.z; yp[3] = (__bf16)o.w;
}

// ---------------- RoPE: Q in place; K -> KR[bh][t][64] pre-swizzled ----------------
__global__ void k_rope(__bf16* __restrict__ Q, const __bf16* __restrict__ Kin,
                       __bf16* __restrict__ KR,
                       const float* __restrict__ cosT, const float* __restrict__ sinT) {
    long total = (long)Mv * 512;
    long i = (long)blockIdx.x * blockDim.x + threadIdx.x;
    if (i >= total) return;
    int row = (int)(i >> 9);
    int p = (int)(i & 511);
    int h = p >> 5, ii = p & 31;
    int t = row & (Tv - 1), b = row >> 11;
    float c = cosT[t * 32 + ii], s = sinT[t * 32 + ii];
    long idx = (long)row * Cv + h * 64 + 2 * ii;
    float x0 = (float)Q[idx], x1 = (float)Q[idx + 1];
    Q[idx]     = (__bf16)(x0 * c - x1 * s);
    Q[idx + 1] = (__bf16)(x0 * s + x1 * c);
    float y0 = (float)Kin[idx], y1 = (float)Kin[idx + 1];
    __bf16 k0 = (__bf16)(y0 * c - y1 * s);
    __bf16 k1 = (__bf16)(y0 * s + y1 * c);
    int bh = b * 16 + h;
    int colb = (4 * ii) ^ ((t & 7) << 4);
    __bf16 pk[2] = {k0, k1};
    *(unsigned int*)((char*)(KR + ((long)bh * Tv + t) * 64) + colb) = *(unsigned int*)pk;
}

// ---------------- V transpose: VT[bh][f][t], pre-swizzled per 64-key tile ----------------
__global__ __launch_bounds__(256) void k_vtrans(const __bf16* __restrict__ V,
                                                __bf16* __restrict__ VT) {
    __shared__ __bf16 Ts[64][72];
    int t0 = blockIdx.x * 64;
    int bh = blockIdx.y, b = bh >> 4, h = bh & 15;
    const long base = ((long)b * Tv) * Cv + h * 64;
    int tid = threadIdx.x;
    int rr = tid >> 3, cc = (tid & 7) * 8;
#pragma unroll
    for (int it = 0; it < 2; ++it) {
        int row = it * 32 + rr;
        *(int4*)&Ts[row][cc] = *(const int4*)(V + base + (long)(t0 + row) * Cv + cc);
    }
    __syncthreads();
#pragma unroll
    for (int it = 0; it < 2; ++it) {
        int f = it * 32 + rr;
        int tcol = cc ^ ((f & 7) << 3);
        __bf16 tmp[8];
#pragma unroll
        for (int j = 0; j < 8; ++j) tmp[j] = Ts[tcol + j][f];
        *(int4*)(VT + ((long)bh * 64 + f) * Tv + t0 + cc) = *(int4*)tmp;
    }
}

// ---------------- GEMM: C[M,N] = A[M,K] @ B[N,K]^T, m97 structure ----------------
template <int BM, int EPI>
__global__ __launch_bounds__(256) void k_gemm(
    const __bf16* __restrict__ A, const __bf16* __restrict__ Bm,
    int M, int N, int K,
    float* __restrict__ outF,
    const float* __restrict__ bias,
    const float* __restrict__ resid,
    __bf16* __restrict__ qOut, __bf16* __restrict__ kOut, __bf16* __restrict__ vOut) {
    constexpr int NN = (BM == 128) ? 4 : 2;
    __shared__ __align__(16) __bf16 As[BM][64];
    __shared__ __align__(16) __bf16 Bs[128][64];
    int tid = threadIdx.x, lane = tid & 63, wave = tid >> 6;
    int m0 = blockIdx.y * BM, n0 = blockIdx.x * 128;
    int wro = (BM == 128) ? (wave >> 1) * 64 : 0;
    int wco = (BM == 128) ? (wave & 1) * 64 : wave * 32;
    int fr = lane & 15, fo = (lane >> 4) * 8;
    int lr = lane >> 3, lc = (lane & 7) * 8;
    f32x4 acc[4][NN] = {};
    for (int k0 = 0; k0 < K; k0 += 64) {
        __syncthreads();
        int arow0 = wave * (BM / 4);
#pragma unroll
        for (int i = 0; i < BM / 32; ++i) {
            int r = arow0 + i * 8 + lr;
            gload_lds16(A + (long)(m0 + r) * K + k0 + lc, &As[r][lc]);
        }
        int brow0 = wave * 32;
#pragma unroll
        for (int i = 0; i < 4; ++i) {
            int r = brow0 + i * 8 + lr;
            gload_lds16(Bm + (long)(n0 + r) * K + k0 + lc, &Bs[r][lc]);
        }
        __syncthreads();
#pragma unroll
        for (int s = 0; s < 2; ++s) {
            bf16x8 af[4], bf[NN];
#pragma unroll
            for (int m = 0; m < 4; ++m)
                af[m] = *(const bf16x8*)(&As[wro + m * 16 + fr][s * 32 + fo]);
#pragma unroll
            for (int n = 0; n < NN; ++n)
                bf[n] = *(const bf16x8*)(&Bs[wco + n * 16 + fr][s * 32 + fo]);
#pragma unroll
            for (int m = 0; m < 4; ++m)
#pragma unroll
                for (int n = 0; n < NN; ++n)
                    acc[m][n] = __builtin_amdgcn_mfma_f32_16x16x32_bf16(af[m], bf[n], acc[m][n], 0, 0, 0);
        }
    }
    int fq = (lane >> 4) * 4;
#pragma unroll
    for (int m = 0; m < 4; ++m)
#pragma unroll
        for (int n = 0; n < NN; ++n) {
            int row = m0 + wro + m * 16 + fq;
            int col = n0 + wco + n * 16 + fr;
#pragma unroll
            for (int r = 0; r < 4; ++r) {
                float v = acc[m][n][r];
                long idx = (long)(row + r) * N + col;
                if (EPI == 1) {
                    if (bias) v += bias[col];
                    if (resid) v += resid[idx];
                    outF[idx] = v;
                } else {
                    int part = col >> 10, c = col & 1023;
                    __bf16* dst = (part == 0) ? qOut : (part == 1) ? kOut : vOut;
                    dst[(long)(row + r) * 1024 + c] = (__bf16)v;
                }
            }
        }
}

// ---------------- fused FFN1+FFN2 ----------------
__global__ __launch_bounds__(256) void k_ffn(const __bf16* __restrict__ A,
                                             const __bf16* __restrict__ B1,
                                             const __bf16* __restrict__ B2,
                                             const float* __restrict__ b1,
                                             const float* __restrict__ b2,
                                             __bf16* __restrict__ outH) {
    __shared__ __align__(16) __bf16 As[128][64];
    __shared__ __align__(16) __bf16 B1s[64][64];
    __shared__ __align__(16) __bf16 B2s[64][64];
    int tid = threadIdx.x, lane = tid & 63, wave = tid >> 6;
    int m0 = blockIdx.y * 128, n0 = blockIdx.x * 64;
    int fr = lane & 15, fo = (lane >> 4) * 8;
    int lr = lane >> 3, lc = (lane & 7) * 8;
    f32x4 acc1[2][4] = {}, acc2[2][4] = {};
    for (int k0 = 0; k0 < Cv; k0 += 64) {
        __syncthreads();
#pragma unroll
        for (int i = 0; i < 4; ++i) {
            int r = wave * 32 + i * 8 + lr;
            gload_lds16(A + (long)(m0 + r) * Cv + k0 + lc, &As[r][lc]);
        }
#pragma unroll
        for (int i = 0; i < 2; ++i) {
            int r = wave * 16 + i * 8 + lr;
            gload_lds16(B1 + (long)(n0 + r) * Cv + k0 + lc, &B1s[r][lc]);
            gload_lds16(B2 + (long)(n0 + r) * Cv + k0 + lc, &B2s[r][lc]);
        }
        __syncthreads();
#pragma unroll
        for (int s = 0; s < 2; ++s) {
            bf16x8 af[2], b1f[4], b2f[4];
#pragma unroll
            for (int m = 0; m < 2; ++m)
                af[m] = *(const bf16x8*)(&As[wave * 32 + m * 16 + fr][s * 32 + fo]);
#pragma unroll
            for (int n = 0; n < 4; ++n) {
                b1f[n] = *(const bf16x8*)(&B1s[n * 16 + fr][s * 32 + fo]);
                b2f[n] = *(const bf16x8*)(&B2s[n * 16 + fr][s * 32 + fo]);
            }
#pragma unroll
            for (int m = 0; m < 2; ++m)
#pragma unroll
                for (int n = 0; n < 4; ++n) {
                    acc1[m][n] = __builtin_amdgcn_mfma_f32_16x16x32_bf16(af[m], b1f[n], acc1[m][n], 0, 0, 0);
                    acc2[m][n] = __builtin_amdgcn_mfma_f32_16x16x32_bf16(af[m], b2f[n], acc2[m][n], 0, 0, 0);
                }
        }
    }
    int fq = (lane >> 4) * 4;
#pragma unroll
    for (int m = 0; m < 2; ++m)
#pragma unroll
        for (int n = 0; n < 4; ++n) {
            int row = m0 + wave * 32 + m * 16 + fq;
            int col = n0 + n * 16 + fr;
            float b1v = (col < HIDv) ? b1[col] : 0.0f;
            float b2v = (col < HIDv) ? b2[col] : 0.0f;
#pragma unroll
            for (int r = 0; r < 4; ++r) {
                float c1 = acc1[m][n][r] + b1v;
                float c2 = acc2[m][n][r] + b2v;
                float sw = c1 * (1.0f + __expf(-c1));
                outH[(long)(row + r) * HIDP + col] = (__bf16)(sw * c2);
            }
        }
}

// ---------------- flash attention: QBLK=32, 2 waves, 2048 blocks (occupancy-first) ----------------
__global__ __launch_bounds__(128) void k_attn(const __bf16* __restrict__ Q,
                                              const __bf16* __restrict__ KR,
                                              const __bf16* __restrict__ VT,
                                              __bf16* __restrict__ O) {
    __shared__ __align__(16) __bf16 Ks[64][64];
    __shared__ __align__(16) __bf16 Vs[64][64];
    __shared__ __align__(16) __bf16 Ps[2][16][64];
    int tid = threadIdx.x, lane = tid & 63, w = tid >> 6;   // w in {0,1}
    int bh = blockIdx.x >> 6;
    int qt = 63 - (blockIdx.x & 63);                        // heavy blocks first
    int q0 = qt * 32;
    int b = bh >> 4, h = bh & 15;
    const long qbase = ((long)b * Tv) * Cv + h * HSv;
    const long kbase = (long)bh * Tv * 64;
    const long vbase = (long)bh * 64 * Tv;
    int fr = lane & 15, fog = lane >> 4;
    int fo = fog * 8, fq = fog * 4;
    int lr = tid >> 3, lc8 = (tid & 7) * 8;                 // staging coords (128 thr)
    int qrow = q0 + w * 16 + fr;
    bf16x8 qf0 = *(const bf16x8*)(Q + qbase + (long)qrow * Cv + fo);
    bf16x8 qf1 = *(const bf16x8*)(Q + qbase + (long)qrow * Cv + 32 + fo);

    const float SCL = 0.125f * 1.44269504f;
    f32x4 o[4] = {};
    float mrow[4], lrow[4];
#pragma unroll
    for (int r = 0; r < 4; ++r) { mrow[r] = -INFINITY; lrow[r] = 0.0f; }

    int nt = (q0 + 95) >> 6;   // tiles covering keys 0 .. q0+31
    for (int t = 0; t < nt; ++t) {
        int j0 = t * 64;
        __syncthreads();
#pragma unroll
        for (int i = 0; i < 4; ++i) {
            int rk = i * 16 + lr;
            gload_lds16(KR + kbase + (long)(j0 + rk) * 64 + lc8, &Ks[rk][lc8]);
            gload_lds16(VT + vbase + (long)rk * Tv + j0 + lc8, &Vs[rk][lc8]);
        }
        __syncthreads();
        // ---- QK^T ----
        f32x4 s4[4];
        __builtin_amdgcn_s_setprio(1);
#pragma unroll
        for (int kk = 0; kk < 4; ++kk) {
            int key = kk * 16 + fr;
            const char* krow = (const char*)&Ks[key][0];
            bf16x8 kf0 = *(const bf16x8*)(krow + ((fo * 2) ^ ((key & 7) << 4)));
            bf16x8 kf1 = *(const bf16x8*)(krow + ((64 + fo * 2) ^ ((key & 7) << 4)));
            f32x4 z = {};
            z = __builtin_amdgcn_mfma_f32_16x16x32_bf16(qf0, kf0, z, 0, 0, 0);
            z = __builtin_amdgcn_mfma_f32_16x16x32_bf16(qf1, kf1, z, 0, 0, 0);
            s4[kk] = z;
        }
        __builtin_amdgcn_s_setprio(0);
        // ---- online softmax ----
        bool last = (t == nt - 1);
#pragma unroll
        for (int r = 0; r < 4; ++r) {
#pragma unroll
            for (int kk = 0; kk < 4; ++kk) {
                float v = s4[kk][r] * SCL;
                if (last) {
                    int key = j0 + kk * 16 + fr;
                    int qr = q0 + w * 16 + fq + r;
                    if (key > qr) v = -INFINITY;
                }
                s4[kk][r] = v;
            }
            float mx = fmaxf(fmaxf(s4[0][r], s4[1][r]), fmaxf(s4[2][r], s4[3][r]));
#pragma unroll
            for (int msk = 1; msk < 16; msk <<= 1) mx = fmaxf(mx, __shfl_xor(mx, msk));
            float mn = fmaxf(mrow[r], mx);
            float alpha = exp2f(mrow[r] - mn);
            mrow[r] = mn;
            float rs = 0.0f;
#pragma unroll
            for (int kk = 0; kk < 4; ++kk) {
                float pv = exp2f(s4[kk][r] - mn);
                s4[kk][r] = pv;
                rs += pv;
            }
#pragma unroll
            for (int msk = 1; msk < 16; msk <<= 1) rs += __shfl_xor(rs, msk);
            lrow[r] = lrow[r] * alpha + rs;
#pragma unroll
            for (int f = 0; f < 4; ++f) o[f][r] *= alpha;
            char* prow = (char*)&Ps[w][fq + r][0];
#pragma unroll
            for (int kk = 0; kk < 4; ++kk) {
                int colb = ((kk * 16 + fr) * 2) ^ (((fq + r) & 7) << 4);
                *(__bf16*)(prow + colb) = (__bf16)s4[kk][r];
            }
        }
        // ---- PV (per-wave P tile, intra-wave dep only) ----
        const char* prd = (const char*)&Ps[w][fr][0];
        bf16x8 pa0 = *(const bf16x8*)(prd + ((fo * 2) ^ ((fr & 7) << 4)));
        bf16x8 pa1 = *(const bf16x8*)(prd + ((64 + fo * 2) ^ ((fr & 7) << 4)));
        __builtin_amdgcn_s_setprio(1);
#pragma unroll
        for (int f = 0; f < 4; ++f) {
            int vrow = f * 16 + fr;
            const char* vrd = (const char*)&Vs[vrow][0];
            bf16x8 v0 = *(const bf16x8*)(vrd + ((fo * 2) ^ ((vrow & 7) << 4)));
            bf16x8 v1 = *(const bf16x8*)(vrd + ((64 + fo * 2) ^ ((vrow & 7) << 4)));
            o[f] = __builtin_amdgcn_mfma_f32_16x16x32_bf16(pa0, v0, o[f], 0, 0, 0);
            o[f] = __builtin_amdgcn_mfma_f32_16x16x32_bf16(pa1, v1, o[f], 0, 0, 0);
        }
        __builtin_amdgcn_s_setprio(0);
    }
#pragma unroll
    for (int f = 0; f < 4; ++f)
#pragma unroll
        for (int r = 0; r < 4; ++r) {
            int row = q0 + w * 16 + fq + r;
            int col = f * 16 + fr;
            O[qbase + (long)row * Cv + col] = (__bf16)(o[f][r] / lrow[r]);
        }
}

// ---------------- launch ----------------
extern "C" void kernel_launch(void* const* d_in, const int* in_sizes, int n_in,
                              void* d_out, int out_size, void* d_ws, size_t ws_size,
                              hipStream_t stream) {
    const float* x    = (const float*)d_in[0];
    const float* ln1w = (const float*)d_in[1];
    const float* Wq   = (const float*)d_in[2];
    const float* Wk   = (const float*)d_in[3];
    const float* Wv   = (const float*)d_in[4];
    const float* Wo   = (const float*)d_in[5];
    const float* bo   = (const float*)d_in[6];
    const float* w1   = (const float*)d_in[7];
    const float* b1   = (const float*)d_in[8];
    const float* w2   = (const float*)d_in[9];
    const float* b2   = (const float*)d_in[10];
    const float* w3   = (const float*)d_in[11];
    const float* b3   = (const float*)d_in[12];
    const float* ln2w = (const float*)d_in[13];
    const float* cosT = (const float*)d_in[14];
    const float* sinT = (const float*)d_in[15];
    float* out = (float*)d_out;

    char* p = (char*)d_ws;
    auto alloc = [&](size_t bytes) {
        char* r = p;
        p += (bytes + 255) & ~(size_t)255;
        return r;
    };
    float*  x1f = (float*)alloc((size_t)Mv * Cv * 4);
    __bf16* qh  = (__bf16*)alloc((size_t)Mv * Cv * 2);
    __bf16* kh  = (__bf16*)alloc((size_t)Mv * Cv * 2);
    __bf16* vh  = (__bf16*)alloc((size_t)Mv * Cv * 2);
    __bf16* ah  = (__bf16*)alloc((size_t)Mv * Cv * 2);
    float*  x3f = (float*)alloc((size_t)Mv * Cv * 4);
    __bf16* x1h = (__bf16*)alloc((size_t)Mv * Cv * 2);
    __bf16* VT  = (__bf16*)x1h;                                   // alias: x1h dead after QKV GEMM
    __bf16* x3h = (__bf16*)alloc((size_t)Mv * Cv * 2);
    __bf16* KR  = (__bf16*)alloc((size_t)Bv * Hv * Tv * HSv * 2);
    __bf16* hh  = (__bf16*)alloc((size_t)Mv * HIDP * 2);
    __bf16* wqkvh = (__bf16*)alloc((size_t)3072 * Cv * 2);
    __bf16* woh = (__bf16*)alloc((size_t)Cv * Cv * 2);
    __bf16* w1h = (__bf16*)alloc((size_t)HIDP * Cv * 2);
    __bf16* w2h = (__bf16*)alloc((size_t)HIDP * Cv * 2);
    __bf16* w3h = (__bf16*)alloc((size_t)Cv * HIDP * 2);

    const long nCC = (long)Cv * Cv;
    CastArgs ca;
    ca.seg[0] = {Wq, wqkvh,           nCC, nCC, 0, 0};
    ca.seg[1] = {Wk, wqkvh + nCC,     nCC, nCC, 0, 0};
    ca.seg[2] = {Wv, wqkvh + 2 * nCC, nCC, nCC, 0, 0};
    ca.seg[3] = {Wo, woh,             nCC, nCC, 0, 0};
    ca.seg[4] = {w1, w1h, (long)HIDv * Cv, (long)HIDP * Cv, 0, 0};
    ca.seg[5] = {w2, w2h, (long)HIDv * Cv, (long)HIDP * Cv, 0, 0};
    ca.seg[6] = {w3, w3h, (long)Cv * HIDv, (long)Cv * HIDP, HIDv, HIDP};
    k_castall<<<2048, 256, 0, stream>>>(ca);

    k_rmsnorm<<<Mv, 256, 0, stream>>>(x, ln1w, x1f, x1h);

    k_gemm<128, 4><<<dim3(24, 32), 256, 0, stream>>>(x1h, wqkvh, Mv, 3072, Cv,
        nullptr, nullptr, nullptr, qh, kh, vh);

    k_rope<<<(Mv * 512 + 255) / 256, 256, 0, stream>>>(qh, kh, KR, cosT, sinT);
    k_vtrans<<<dim3(Tv / 64, Bv * Hv), 256, 0, stream>>>(vh, VT);

    k_attn<<<2048, 128, 0, stream>>>(qh, KR, VT, ah);

    k_gemm<64, 1><<<dim3(8, 64), 256, 0, stream>>>(ah, woh, Mv, Cv, Cv,
        x1f, bo, x1f, nullptr, nullptr, nullptr);

    k_rmsnorm<<<Mv, 256, 0, stream>>>(x1f, ln2w, x3f, x3h);

    k_ffn<<<dim3(HIDP / 64, 32), 256, 0, stream>>>(x3h, w1h, w2h, b1, b2, hh);

    k_gemm<64, 1><<<dim3(8, 64), 256, 0, stream>>>(hh, w3h, Mv, Cv, HIDP,
        out, b3, x3f, nullptr, nullptr, nullptr);
}

// Round 5
// 343.439 us; speedup vs baseline: 1.1219x; 1.1219x over previous
//
#include <hip/hip_runtime.h>
#include <hip/hip_bf16.h>

#define Bv 2
#define Tv 2048
#define Cv 1024
#define Hv 16
#define HSv 64
#define HIDv 2730
#define HIDP 2816
#define Mv 4096

using bf16x8 = __attribute__((ext_vector_type(8))) __bf16;
using f32x4  = __attribute__((ext_vector_type(4))) float;
typedef unsigned long long ull;

__device__ __forceinline__ void gload_lds16(const void* g, void* l) {
    auto gp = (const __attribute__((address_space(1))) unsigned int*)(unsigned long long)(uintptr_t)g;
    auto lp = (__attribute__((address_space(3))) unsigned int*)(unsigned int)(uintptr_t)l;
    __builtin_amdgcn_global_load_lds(gp, lp, 16, 0, 0);
}

// ---------------- fused weight cast ----------------
struct CastSeg { const float* s; __bf16* d; long nsrc; long ntot; int sc; int dc; };
struct CastArgs { CastSeg seg[7]; };

__global__ __launch_bounds__(256) void k_castall(CastArgs a) {
    long gid = (long)blockIdx.x * 256 + threadIdx.x;
    long gstr = (long)gridDim.x * 256;
#pragma unroll 1
    for (int g = 0; g < 7; ++g) {
        CastSeg sg = a.seg[g];
        if (sg.sc == 0) {
            long n4 = sg.ntot >> 2;
            for (long i = gid; i < n4; i += gstr) {
                long base = i * 4;
                float4 v = {0.f, 0.f, 0.f, 0.f};
                if (base < sg.nsrc) v = *(const float4*)(sg.s + base);
                __bf16 o[4] = {(__bf16)v.x, (__bf16)v.y, (__bf16)v.z, (__bf16)v.w};
                *(ull*)(sg.d + base) = *(ull*)o;
            }
        } else {
            for (long i = gid; i < sg.ntot; i += gstr) {
                int r = (int)(i / sg.dc), c = (int)(i % sg.dc);
                sg.d[i] = (c < sg.sc) ? (__bf16)sg.s[(long)r * sg.sc + c] : (__bf16)0.0f;
            }
        }
    }
}

// ---------------- rmsnorm ----------------
__global__ __launch_bounds__(256) void k_rmsnorm(const float* __restrict__ x,
                                                 const float* __restrict__ w,
                                                 float* __restrict__ yf,
                                                 __bf16* __restrict__ yh) {
    int row = blockIdx.x;
    const float4* xr = (const float4*)(x + (size_t)row * Cv);
    float4 a = xr[threadIdx.x];
    float ss = a.x * a.x + a.y * a.y + a.z * a.z + a.w * a.w;
#pragma unroll
    for (int m = 1; m < 64; m <<= 1) ss += __shfl_xor(ss, m);
    __shared__ float red[4];
    if ((threadIdx.x & 63) == 0) red[threadIdx.x >> 6] = ss;
    __syncthreads();
    float tot = red[0] + red[1] + red[2] + red[3];
    float sc = rsqrtf(tot * (1.0f / Cv) + 1e-6f);
    float4 wv = ((const float4*)w)[threadIdx.x];
    float4 o;
    o.x = a.x * sc * wv.x; o.y = a.y * sc * wv.y;
    o.z = a.z * sc * wv.z; o.w = a.w * sc * wv.w;
    ((float4*)(yf + (size_t)row * Cv))[threadIdx.x] = o;
    __bf16* yp = yh + (size_t)row * Cv + threadIdx.x * 4;
    yp[0] = (__bf16)o.x; yp[1] = (__bf16)o.y; yp[2] = (__bf16)o.z; yp[3] = (__bf16)o.w;
}

// ---------------- RoPE: Q in place; K -> KR[bh][t][64] pre-swizzled ----------------
__global__ void k_rope(__bf16* __restrict__ Q, const __bf16* __restrict__ Kin,
                       __bf16* __restrict__ KR,
                       const float* __restrict__ cosT, const float* __restrict__ sinT) {
    long total = (long)Mv * 512;
    long i = (long)blockIdx.x * blockDim.x + threadIdx.x;
    if (i >= total) return;
    int row = (int)(i >> 9);
    int p = (int)(i & 511);
    int h = p >> 5, ii = p & 31;
    int t = row & (Tv - 1), b = row >> 11;
    float c = cosT[t * 32 + ii], s = sinT[t * 32 + ii];
    long idx = (long)row * Cv + h * 64 + 2 * ii;
    float x0 = (float)Q[idx], x1 = (float)Q[idx + 1];
    Q[idx]     = (__bf16)(x0 * c - x1 * s);
    Q[idx + 1] = (__bf16)(x0 * s + x1 * c);
    float y0 = (float)Kin[idx], y1 = (float)Kin[idx + 1];
    __bf16 k0 = (__bf16)(y0 * c - y1 * s);
    __bf16 k1 = (__bf16)(y0 * s + y1 * c);
    int bh = b * 16 + h;
    int colb = (4 * ii) ^ ((t & 7) << 4);
    __bf16 pk[2] = {k0, k1};
    *(unsigned int*)((char*)(KR + ((long)bh * Tv + t) * 64) + colb) = *(unsigned int*)pk;
}

// ---------------- V transpose: VT[bh][f][t], pre-swizzled per 64-key tile ----------------
__global__ __launch_bounds__(256) void k_vtrans(const __bf16* __restrict__ V,
                                                __bf16* __restrict__ VT) {
    __shared__ __bf16 Ts[64][72];
    int t0 = blockIdx.x * 64;
    int bh = blockIdx.y, b = bh >> 4, h = bh & 15;
    const long base = ((long)b * Tv) * Cv + h * 64;
    int tid = threadIdx.x;
    int rr = tid >> 3, cc = (tid & 7) * 8;
#pragma unroll
    for (int it = 0; it < 2; ++it) {
        int row = it * 32 + rr;
        *(int4*)&Ts[row][cc] = *(const int4*)(V + base + (long)(t0 + row) * Cv + cc);
    }
    __syncthreads();
#pragma unroll
    for (int it = 0; it < 2; ++it) {
        int f = it * 32 + rr;
        int tcol = cc ^ ((f & 7) << 3);
        __bf16 tmp[8];
#pragma unroll
        for (int j = 0; j < 8; ++j) tmp[j] = Ts[tcol + j][f];
        *(int4*)(VT + ((long)bh * 64 + f) * Tv + t0 + cc) = *(int4*)tmp;
    }
}

// ---------------- GEMM: C[M,N] = A[M,K] @ B[N,K]^T, m97 structure ----------------
template <int BM, int EPI>
__global__ __launch_bounds__(256) void k_gemm(
    const __bf16* __restrict__ A, const __bf16* __restrict__ Bm,
    int M, int N, int K,
    float* __restrict__ outF,
    const float* __restrict__ bias,
    const float* __restrict__ resid,
    __bf16* __restrict__ qOut, __bf16* __restrict__ kOut, __bf16* __restrict__ vOut) {
    constexpr int NN = (BM == 128) ? 4 : 2;
    __shared__ __align__(16) __bf16 As[BM][64];
    __shared__ __align__(16) __bf16 Bs[128][64];
    int tid = threadIdx.x, lane = tid & 63, wave = tid >> 6;
    int m0 = blockIdx.y * BM, n0 = blockIdx.x * 128;
    int wro = (BM == 128) ? (wave >> 1) * 64 : 0;
    int wco = (BM == 128) ? (wave & 1) * 64 : wave * 32;
    int fr = lane & 15, fo = (lane >> 4) * 8;
    int lr = lane >> 3, lc = (lane & 7) * 8;
    f32x4 acc[4][NN] = {};
    for (int k0 = 0; k0 < K; k0 += 64) {
        __syncthreads();
        int arow0 = wave * (BM / 4);
#pragma unroll
        for (int i = 0; i < BM / 32; ++i) {
            int r = arow0 + i * 8 + lr;
            gload_lds16(A + (long)(m0 + r) * K + k0 + lc, &As[r][lc]);
        }
        int brow0 = wave * 32;
#pragma unroll
        for (int i = 0; i < 4; ++i) {
            int r = brow0 + i * 8 + lr;
            gload_lds16(Bm + (long)(n0 + r) * K + k0 + lc, &Bs[r][lc]);
        }
        __syncthreads();
#pragma unroll
        for (int s = 0; s < 2; ++s) {
            bf16x8 af[4], bf[NN];
#pragma unroll
            for (int m = 0; m < 4; ++m)
                af[m] = *(const bf16x8*)(&As[wro + m * 16 + fr][s * 32 + fo]);
#pragma unroll
            for (int n = 0; n < NN; ++n)
                bf[n] = *(const bf16x8*)(&Bs[wco + n * 16 + fr][s * 32 + fo]);
#pragma unroll
            for (int m = 0; m < 4; ++m)
#pragma unroll
                for (int n = 0; n < NN; ++n)
                    acc[m][n] = __builtin_amdgcn_mfma_f32_16x16x32_bf16(af[m], bf[n], acc[m][n], 0, 0, 0);
        }
    }
    int fq = (lane >> 4) * 4;
#pragma unroll
    for (int m = 0; m < 4; ++m)
#pragma unroll
        for (int n = 0; n < NN; ++n) {
            int row = m0 + wro + m * 16 + fq;
            int col = n0 + wco + n * 16 + fr;
#pragma unroll
            for (int r = 0; r < 4; ++r) {
                float v = acc[m][n][r];
                long idx = (long)(row + r) * N + col;
                if (EPI == 1) {
                    if (bias) v += bias[col];
                    if (resid) v += resid[idx];
                    outF[idx] = v;
                } else {
                    int part = col >> 10, c = col & 1023;
                    __bf16* dst = (part == 0) ? qOut : (part == 1) ? kOut : vOut;
                    dst[(long)(row + r) * 1024 + c] = (__bf16)v;
                }
            }
        }
}

// ---------------- fused FFN1+FFN2 ----------------
__global__ __launch_bounds__(256) void k_ffn(const __bf16* __restrict__ A,
                                             const __bf16* __restrict__ B1,
                                             const __bf16* __restrict__ B2,
                                             const float* __restrict__ b1,
                                             const float* __restrict__ b2,
                                             __bf16* __restrict__ outH) {
    __shared__ __align__(16) __bf16 As[128][64];
    __shared__ __align__(16) __bf16 B1s[64][64];
    __shared__ __align__(16) __bf16 B2s[64][64];
    int tid = threadIdx.x, lane = tid & 63, wave = tid >> 6;
    int m0 = blockIdx.y * 128, n0 = blockIdx.x * 64;
    int fr = lane & 15, fo = (lane >> 4) * 8;
    int lr = lane >> 3, lc = (lane & 7) * 8;
    f32x4 acc1[2][4] = {}, acc2[2][4] = {};
    for (int k0 = 0; k0 < Cv; k0 += 64) {
        __syncthreads();
#pragma unroll
        for (int i = 0; i < 4; ++i) {
            int r = wave * 32 + i * 8 + lr;
            gload_lds16(A + (long)(m0 + r) * Cv + k0 + lc, &As[r][lc]);
        }
#pragma unroll
        for (int i = 0; i < 2; ++i) {
            int r = wave * 16 + i * 8 + lr;
            gload_lds16(B1 + (long)(n0 + r) * Cv + k0 + lc, &B1s[r][lc]);
            gload_lds16(B2 + (long)(n0 + r) * Cv + k0 + lc, &B2s[r][lc]);
        }
        __syncthreads();
#pragma unroll
        for (int s = 0; s < 2; ++s) {
            bf16x8 af[2], b1f[4], b2f[4];
#pragma unroll
            for (int m = 0; m < 2; ++m)
                af[m] = *(const bf16x8*)(&As[wave * 32 + m * 16 + fr][s * 32 + fo]);
#pragma unroll
            for (int n = 0; n < 4; ++n) {
                b1f[n] = *(const bf16x8*)(&B1s[n * 16 + fr][s * 32 + fo]);
                b2f[n] = *(const bf16x8*)(&B2s[n * 16 + fr][s * 32 + fo]);
            }
#pragma unroll
            for (int m = 0; m < 2; ++m)
#pragma unroll
                for (int n = 0; n < 4; ++n) {
                    acc1[m][n] = __builtin_amdgcn_mfma_f32_16x16x32_bf16(af[m], b1f[n], acc1[m][n], 0, 0, 0);
                    acc2[m][n] = __builtin_amdgcn_mfma_f32_16x16x32_bf16(af[m], b2f[n], acc2[m][n], 0, 0, 0);
                }
        }
    }
    int fq = (lane >> 4) * 4;
#pragma unroll
    for (int m = 0; m < 2; ++m)
#pragma unroll
        for (int n = 0; n < 4; ++n) {
            int row = m0 + wave * 32 + m * 16 + fq;
            int col = n0 + n * 16 + fr;
            float b1v = (col < HIDv) ? b1[col] : 0.0f;
            float b2v = (col < HIDv) ? b2[col] : 0.0f;
#pragma unroll
            for (int r = 0; r < 4; ++r) {
                float c1 = acc1[m][n][r] + b1v;
                float c2 = acc2[m][n][r] + b2v;
                float sw = c1 * (1.0f + __expf(-c1));
                outH[(long)(row + r) * HIDP + col] = (__bf16)(sw * c2);
            }
        }
}

// ---------------- flash attention: swapped-operand MFMA, lane-local softmax ----------------
// S^T = mfma(K,Q): lane owns qrow = q0+w*16+(lane&15); 16 P-values in regs;
// row-reduce = in-lane + 2 shfl hops. PV: O^T = mfma(V^T, P^T).
__global__ __launch_bounds__(256) void k_attn(const __bf16* __restrict__ Q,
                                              const __bf16* __restrict__ KR,
                                              const __bf16* __restrict__ VT,
                                              __bf16* __restrict__ O) {
    __shared__ __align__(16) __bf16 Ks[64][64];
    __shared__ __align__(16) __bf16 Vs[64][64];
    __shared__ __align__(16) __bf16 Ps[4][16][64];
    int tid = threadIdx.x, lane = tid & 63, w = tid >> 6;
    int bh = blockIdx.x >> 5;
    int qt = 31 - (blockIdx.x & 31);          // heavy blocks first
    int q0 = qt * 64;
    int b = bh >> 4, h = bh & 15;
    const long qbase = ((long)b * Tv) * Cv + h * HSv;
    const long kbase = (long)bh * Tv * 64;
    const long vbase = (long)bh * 64 * Tv;
    int fr = lane & 15, g = lane >> 4;
    int go = g * 8;
    int lr = lane >> 3, lc8 = (lane & 7) * 8;
    int xr = (fr & 7) << 4;                   // per-row swizzle XOR (byte units)
    int qrow = q0 + w * 16 + fr;
    bf16x8 qf0 = *(const bf16x8*)(Q + qbase + (long)qrow * Cv + go);
    bf16x8 qf1 = *(const bf16x8*)(Q + qbase + (long)qrow * Cv + 32 + go);

    const float SCL = 0.125f * 1.44269504f;   // (1/sqrt(64)) * log2(e)
    f32x4 o[4] = {};
    float mrow = -INFINITY, lrow = 0.0f;

    for (int j0 = 0; j0 <= q0; j0 += 64) {
        __syncthreads();
#pragma unroll
        for (int i = 0; i < 2; ++i) {
            int rk = w * 16 + i * 8 + lr;
            gload_lds16(KR + kbase + (long)(j0 + rk) * 64 + lc8, &Ks[rk][lc8]);
            gload_lds16(VT + vbase + (long)rk * Tv + j0 + lc8, &Vs[rk][lc8]);
        }
        __syncthreads();
        // ---- QK^T (swapped: A=K, B=Q -> D[key][qrow]) ----
        f32x4 s4[4];
        __builtin_amdgcn_s_setprio(1);
#pragma unroll
        for (int kk = 0; kk < 4; ++kk) {
            int key = kk * 16 + fr;
            const char* krow = (const char*)&Ks[key][0];
            bf16x8 kf0 = *(const bf16x8*)(krow + ((go * 2) ^ ((key & 7) << 4)));
            bf16x8 kf1 = *(const bf16x8*)(krow + ((64 + go * 2) ^ ((key & 7) << 4)));
            f32x4 z = {};
            z = __builtin_amdgcn_mfma_f32_16x16x32_bf16(kf0, qf0, z, 0, 0, 0);
            z = __builtin_amdgcn_mfma_f32_16x16x32_bf16(kf1, qf1, z, 0, 0, 0);
            s4[kk] = z;
        }
        __builtin_amdgcn_s_setprio(0);
        // ---- scale + causal mask (lane-local: s4[kk][r] = S[kk*16+g*4+r][qrow]) ----
        bool diag = (j0 == q0);
        if (diag) {
            int qloc = w * 16 + fr;
#pragma unroll
            for (int kk = 0; kk < 4; ++kk)
#pragma unroll
                for (int r = 0; r < 4; ++r) {
                    int key = kk * 16 + g * 4 + r;
                    s4[kk][r] = (key > qloc) ? -INFINITY : s4[kk][r] * SCL;
                }
        } else {
#pragma unroll
            for (int kk = 0; kk < 4; ++kk)
#pragma unroll
                for (int r = 0; r < 4; ++r) s4[kk][r] *= SCL;
        }
        // ---- online softmax: in-lane over 16, then 2 shfl hops ----
        float pmax = s4[0][0];
#pragma unroll
        for (int kk = 0; kk < 4; ++kk)
#pragma unroll
            for (int r = 0; r < 4; ++r) pmax = fmaxf(pmax, s4[kk][r]);
        pmax = fmaxf(pmax, __shfl_xor(pmax, 16));
        pmax = fmaxf(pmax, __shfl_xor(pmax, 32));
        float mn = fmaxf(mrow, pmax);
        float alpha = exp2f(mrow - mn);
        mrow = mn;
        float rs = 0.0f;
#pragma unroll
        for (int kk = 0; kk < 4; ++kk)
#pragma unroll
            for (int r = 0; r < 4; ++r) {
                float pv = exp2f(s4[kk][r] - mn);
                s4[kk][r] = pv;
                rs += pv;
            }
        rs += __shfl_xor(rs, 16);
        rs += __shfl_xor(rs, 32);
        lrow = lrow * alpha + rs;
#pragma unroll
        for (int fb = 0; fb < 4; ++fb)
#pragma unroll
            for (int r = 0; r < 4; ++r) o[fb][r] *= alpha;
        // ---- P -> LDS (per-wave, swizzled, 4x 8B stores) ----
        char* prow = (char*)&Ps[w][fr][0];
#pragma unroll
        for (int kk = 0; kk < 4; ++kk) {
            __bf16 pk[4] = {(__bf16)s4[kk][0], (__bf16)s4[kk][1],
                            (__bf16)s4[kk][2], (__bf16)s4[kk][3]};
            *(ull*)(prow + ((kk * 32 + g * 8) ^ xr)) = *(ull*)pk;
        }
        // ---- PV (swapped: A=V^T, B=P^T -> D[f][qrow]) ----
        const char* prd = prow;
        bf16x8 pa0 = *(const bf16x8*)(prd + ((g * 16) ^ xr));
        bf16x8 pa1 = *(const bf16x8*)(prd + ((64 + g * 16) ^ xr));
        __builtin_amdgcn_s_setprio(1);
#pragma unroll
        for (int fb = 0; fb < 4; ++fb) {
            int vrow = fb * 16 + fr;
            const char* vrd = (const char*)&Vs[vrow][0];
            bf16x8 v0 = *(const bf16x8*)(vrd + ((go * 2) ^ ((vrow & 7) << 4)));
            bf16x8 v1 = *(const bf16x8*)(vrd + ((64 + go * 2) ^ ((vrow & 7) << 4)));
            o[fb] = __builtin_amdgcn_mfma_f32_16x16x32_bf16(v0, pa0, o[fb], 0, 0, 0);
            o[fb] = __builtin_amdgcn_mfma_f32_16x16x32_bf16(v1, pa1, o[fb], 0, 0, 0);
        }
        __builtin_amdgcn_s_setprio(0);
    }
    // ---- epilogue: lane owns qrow; o[fb][r] = O[qrow][fb*16+g*4+r] ----
    float rl = 1.0f / lrow;
#pragma unroll
    for (int fb = 0; fb < 4; ++fb) {
        __bf16 ov[4];
#pragma unroll
        for (int r = 0; r < 4; ++r) ov[r] = (__bf16)(o[fb][r] * rl);
        *(ull*)(O + qbase + (long)qrow * Cv + fb * 16 + g * 4) = *(ull*)ov;
    }
}

// ---------------- launch ----------------
extern "C" void kernel_launch(void* const* d_in, const int* in_sizes, int n_in,
                              void* d_out, int out_size, void* d_ws, size_t ws_size,
                              hipStream_t stream) {
    const float* x    = (const float*)d_in[0];
    const float* ln1w = (const float*)d_in[1];
    const float* Wq   = (const float*)d_in[2];
    const float* Wk   = (const float*)d_in[3];
    const float* Wv   = (const float*)d_in[4];
    const float* Wo   = (const float*)d_in[5];
    const float* bo   = (const float*)d_in[6];
    const float* w1   = (const float*)d_in[7];
    const float* b1   = (const float*)d_in[8];
    const float* w2   = (const float*)d_in[9];
    const float* b2   = (const float*)d_in[10];
    const float* w3   = (const float*)d_in[11];
    const float* b3   = (const float*)d_in[12];
    const float* ln2w = (const float*)d_in[13];
    const float* cosT = (const float*)d_in[14];
    const float* sinT = (const float*)d_in[15];
    float* out = (float*)d_out;

    char* p = (char*)d_ws;
    auto alloc = [&](size_t bytes) {
        char* r = p;
        p += (bytes + 255) & ~(size_t)255;
        return r;
    };
    float*  x1f = (float*)alloc((size_t)Mv * Cv * 4);
    __bf16* qh  = (__bf16*)alloc((size_t)Mv * Cv * 2);
    __bf16* kh  = (__bf16*)alloc((size_t)Mv * Cv * 2);
    __bf16* vh  = (__bf16*)alloc((size_t)Mv * Cv * 2);
    __bf16* ah  = (__bf16*)alloc((size_t)Mv * Cv * 2);
    float*  x3f = (float*)alloc((size_t)Mv * Cv * 4);
    __bf16* x1h = (__bf16*)alloc((size_t)Mv * Cv * 2);
    __bf16* VT  = (__bf16*)x1h;                                   // alias: x1h dead after QKV GEMM
    __bf16* x3h = (__bf16*)alloc((size_t)Mv * Cv * 2);
    __bf16* KR  = (__bf16*)alloc((size_t)Bv * Hv * Tv * HSv * 2);
    __bf16* hh  = (__bf16*)alloc((size_t)Mv * HIDP * 2);
    __bf16* wqkvh = (__bf16*)alloc((size_t)3072 * Cv * 2);
    __bf16* woh = (__bf16*)alloc((size_t)Cv * Cv * 2);
    __bf16* w1h = (__bf16*)alloc((size_t)HIDP * Cv * 2);
    __bf16* w2h = (__bf16*)alloc((size_t)HIDP * Cv * 2);
    __bf16* w3h = (__bf16*)alloc((size_t)Cv * HIDP * 2);

    const long nCC = (long)Cv * Cv;
    CastArgs ca;
    ca.seg[0] = {Wq, wqkvh,           nCC, nCC, 0, 0};
    ca.seg[1] = {Wk, wqkvh + nCC,     nCC, nCC, 0, 0};
    ca.seg[2] = {Wv, wqkvh + 2 * nCC, nCC, nCC, 0, 0};
    ca.seg[3] = {Wo, woh,             nCC, nCC, 0, 0};
    ca.seg[4] = {w1, w1h, (long)HIDv * Cv, (long)HIDP * Cv, 0, 0};
    ca.seg[5] = {w2, w2h, (long)HIDv * Cv, (long)HIDP * Cv, 0, 0};
    ca.seg[6] = {w3, w3h, (long)Cv * HIDv, (long)Cv * HIDP, HIDv, HIDP};
    k_castall<<<2048, 256, 0, stream>>>(ca);

    k_rmsnorm<<<Mv, 256, 0, stream>>>(x, ln1w, x1f, x1h);

    k_gemm<128, 4><<<dim3(24, 32), 256, 0, stream>>>(x1h, wqkvh, Mv, 3072, Cv,
        nullptr, nullptr, nullptr, qh, kh, vh);

    k_rope<<<(Mv * 512 + 255) / 256, 256, 0, stream>>>(qh, kh, KR, cosT, sinT);
    k_vtrans<<<dim3(Tv / 64, Bv * Hv), 256, 0, stream>>>(vh, VT);

    k_attn<<<1024, 256, 0, stream>>>(qh, KR, VT, ah);

    k_gemm<64, 1><<<dim3(8, 64), 256, 0, stream>>>(ah, woh, Mv, Cv, Cv,
        x1f, bo, x1f, nullptr, nullptr, nullptr);

    k_rmsnorm<<<Mv, 256, 0, stream>>>(x1f, ln2w, x3f, x3h);

    k_ffn<<<dim3(HIDP / 64, 32), 256, 0, stream>>>(x3h, w1h, w2h, b1, b2, hh);

    k_gemm<64, 1><<<dim3(8, 64), 256, 0, stream>>>(hh, w3h, Mv, Cv, HIDP,
        out, b3, x3f, nullptr, nullptr, nullptr);
}